// Round 6
// baseline (99.561 us; speedup 1.0000x reference)
//
#include <hip/hip_runtime.h>

// DUDCLoss: B=4096, C=1024, K=8, eps=1e-5
// loss = para*loss_multi + (1-para)*loss_single
//
// Exact identity: log(e_c/Z_j + eps) = log(e_c + eps*Z_j) - log(Z_j), Z_j = Sneg + pe_j.
// j-elimination (validated R3/R4, absmax 0.0): a_c = e_c + eps*Sneg, d_j = eps*pe_j <= 1e-5,
//   log(a_c + d_j) ~= log(a_c) + d_j/a_c - 0.5 (d_j/a_c)^2
// => 6 j-independent reductions (L,R,Q each direction).
// target input never read: masked sums = unmasked sums - positive-column terms
// recomputed bitwise-identically from x[pos] (lanes 0..7).
//
// Structure: wave-per-row, shuffle-only reductions, no LDS/barriers/atomics.
// (R3 lesson: per-block same-address atomics + threadfence serialized the grid
// at ~44ns/block — two-kernel reduce is strictly better.)
// R4 lesson: harness overhead (256MB ws 0xAA poison at HBM rate ~42us + input
// restore + graph gaps) dominates total; kernels are ~13us of 93us.
// R5 lesson: __builtin_nontemporal_load needs a clang ext_vector_type, not
// HIP's float4 struct.

constexpr int B_ = 4096;
constexpr int C_ = 1024;
constexpr int K_ = 8;
constexpr float EPSF = 1e-5f;
constexpr float L2E = 1.44269504088896340736f;  // log2(e)
constexpr float LN2 = 0.69314718055994530942f;  // ln(2)

typedef float floatx4 __attribute__((ext_vector_type(4)));

// v_exp_f32: 2^x ; v_log_f32: log2(x) ; v_rcp_f32: 1/x
#if __has_builtin(__builtin_amdgcn_exp2f)
__device__ __forceinline__ float fexp2(float x) { return __builtin_amdgcn_exp2f(x); }
#else
__device__ __forceinline__ float fexp2(float x) { return exp2f(x); }
#endif
#if __has_builtin(__builtin_amdgcn_logf)
__device__ __forceinline__ float flog2(float x) { return __builtin_amdgcn_logf(x); }
#else
__device__ __forceinline__ float flog2(float x) { return log2f(x); }
#endif
#if __has_builtin(__builtin_amdgcn_rcpf)
__device__ __forceinline__ float frcp(float x) { return __builtin_amdgcn_rcpf(x); }
#else
__device__ __forceinline__ float frcp(float x) { return 1.0f / x; }
#endif

__device__ __forceinline__ floatx4 nt_load4(const float* p) {
  return __builtin_nontemporal_load((const floatx4*)p);
}

__global__ __launch_bounds__(256) void dudc_rows(
    const float* __restrict__ out1, const float* __restrict__ out2,
    const int* __restrict__ pos_idx,
    float* __restrict__ ws_multi, float* __restrict__ ws_single)
{
  const int t = threadIdx.x;
  const int wid = t >> 6, lane = t & 63;
  const int row = (blockIdx.x << 2) + wid;

  const float* x1p = out1 + (size_t)row * C_;
  const float* x2p = out2 + (size_t)row * C_;

  // lane owns columns 4*lane + 256*u, u=0..3 (each dwordx4 load is 1KB coalesced)
  float x1[16], x2[16];
#pragma unroll
  for (int u = 0; u < 4; ++u) {
    floatx4 a = nt_load4(x1p + ((lane + (u << 6)) << 2));
    floatx4 b = nt_load4(x2p + ((lane + (u << 6)) << 2));
    x1[4*u+0]=a.x; x1[4*u+1]=a.y; x1[4*u+2]=a.z; x1[4*u+3]=a.w;
    x2[4*u+0]=b.x; x2[4*u+1]=b.y; x2[4*u+2]=b.z; x2[4*u+3]=b.w;
  }

  // positive logits (lanes 0..7; rows are cache-hot from the streaming loads)
  float xp1 = 0.f, xp2 = 0.f;
  if (lane < K_) {
    int p = pos_idx[row * K_ + lane];
    xp1 = x1p[p];
    xp2 = x2p[p];
  }

  // ---- row max (butterfly -> all lanes) ----
  float m1 = x1[0], m2 = x2[0];
#pragma unroll
  for (int i = 1; i < 16; ++i) { m1 = fmaxf(m1, x1[i]); m2 = fmaxf(m2, x2[i]); }
#pragma unroll
  for (int o = 1; o < 64; o <<= 1) {
    m1 = fmaxf(m1, __shfl_xor(m1, o));
    m2 = fmaxf(m2, __shfl_xor(m2, o));
  }
  const float m1l = m1 * L2E, m2l = m2 * L2E;

  float pe1 = 0.f, pe2 = 0.f;
  if (lane < K_) {
    pe1 = fexp2(__builtin_fmaf(xp1, L2E, -m1l));  // identical ops to e at pos
    pe2 = fexp2(__builtin_fmaf(xp2, L2E, -m2l));
  }

  // ---- exps (overwrite x), unmasked sums, sigmoid-CE ----
  float S1 = 0.f, S2 = 0.f, lm2 = 0.f;
#pragma unroll
  for (int i = 0; i < 16; ++i) {
    float e1 = fexp2(__builtin_fmaf(x1[i], L2E, -m1l));
    float e2 = fexp2(__builtin_fmaf(x2[i], L2E, -m2l));
    float s1 = frcp(1.f + fexp2(-L2E * x1[i]));
    float s2 = frcp(1.f + fexp2(-L2E * x2[i]));
    lm2 += s1 * flog2(s2 + EPSF) + s2 * flog2(s1 + EPSF);
    S1 += e1; S2 += e2;
    x1[i] = e1; x2[i] = e2;
  }
  // P1/P2 live only in lanes 0..7: 3 xor rounds + broadcast from lane 0
  float P1 = pe1, P2 = pe2;
#pragma unroll
  for (int o = 1; o < 8; o <<= 1) { P1 += __shfl_xor(P1, o); P2 += __shfl_xor(P2, o); }
  P1 = __shfl(P1, 0); P2 = __shfl(P2, 0);
#pragma unroll
  for (int o = 1; o < 64; o <<= 1) {
    S1 += __shfl_xor(S1, o);  S2 += __shfl_xor(S2, o);
    lm2 += __shfl_xor(lm2, o);
  }
  const float Sn1 = S1 - P1, Sn2 = S2 - P2;   // negative-set sums
  const float es1 = EPSF * Sn1, es2 = EPSF * Sn2;

  // ---- hot loop: 6 unmasked reductions ----
  float L12=0.f, R12=0.f, Q12=0.f, L21=0.f, R21=0.f, Q21=0.f;
#pragma unroll
  for (int i = 0; i < 16; ++i) {
    float a1 = x1[i] + es1, a2 = x2[i] + es2;
    float l1 = flog2(a1),  l2 = flog2(a2);
    float r1 = frcp(a1),   r2 = frcp(a2);
    L12 = __builtin_fmaf(x1[i], l2, L12);
    float t12 = x1[i] * r2;  R12 += t12;  Q12 = __builtin_fmaf(t12, r2, Q12);
    L21 = __builtin_fmaf(x2[i], l1, L21);
    float t21 = x2[i] * r1;  R21 += t21;  Q21 = __builtin_fmaf(t21, r1, Q21);
  }
#pragma unroll
  for (int o = 1; o < 64; o <<= 1) {
    L12 += __shfl_xor(L12,o); R12 += __shfl_xor(R12,o); Q12 += __shfl_xor(Q12,o);
    L21 += __shfl_xor(L21,o); R21 += __shfl_xor(R21,o); Q21 += __shfl_xor(Q21,o);
  }

  // ---- subtract the K positive columns' contributions (lanes 0..7) ----
  float cL12=0.f,cR12=0.f,cQ12=0.f,cL21=0.f,cR21=0.f,cQ21=0.f;
  if (lane < K_) {
    float a2p = pe2 + es2, a1p = pe1 + es1;
    float r2p = frcp(a2p), r1p = frcp(a1p);
    cL12 = pe1 * flog2(a2p);  cR12 = pe1 * r2p;  cQ12 = cR12 * r2p;
    cL21 = pe2 * flog2(a1p);  cR21 = pe2 * r1p;  cQ21 = cR21 * r1p;
  }
#pragma unroll
  for (int o = 1; o < 8; o <<= 1) {
    cL12 += __shfl_xor(cL12,o); cR12 += __shfl_xor(cR12,o); cQ12 += __shfl_xor(cQ12,o);
    cL21 += __shfl_xor(cL21,o); cR21 += __shfl_xor(cR21,o); cQ21 += __shfl_xor(cQ21,o);
  }

  // ---- per-j epilogue (lane = j) ----
  float contv = 0.f;
  if (lane < K_) {
    float sL12 = L12 - cL12, sR12 = R12 - cR12, sQ12 = Q12 - cQ12;
    float sL21 = L21 - cL21, sR21 = R21 - cR21, sQ21 = Q21 - cQ21;
    float Z1 = Sn1 + pe1, Z2 = Sn2 + pe2;
    float d1 = EPSF * pe1, d2 = EPSF * pe2;
    float T1 = LN2*sL12 + d2*sR12 - 0.5f*d2*d2*sQ12;
    float T2 = LN2*sL21 + d1*sR21 - 0.5f*d1*d1*sQ21;
    float pt1 = pe1 * (LN2 * flog2(pe2 + EPSF*Z2));
    float pt2 = pe2 * (LN2 * flog2(pe1 + EPSF*Z1));
    float x12 = -(T1 + pt1) * frcp(Z1) + LN2 * flog2(Z2);
    float x21 = -(T2 + pt2) * frcp(Z2) + LN2 * flog2(Z1);
    contv = x12 + x21;
  }
  contv += __shfl_down(contv, 4);
  contv += __shfl_down(contv, 2);
  contv += __shfl_down(contv, 1);
  if (lane == 0) {
    ws_multi[row]  = -LN2 * lm2;   // per-row sigmoid-CE sum (both directions)
    ws_single[row] = contv;        // per-row sum over K (scaled in final)
  }
}

// single-wave finalize: 8KB of partials, no LDS, no __syncthreads
__global__ __launch_bounds__(64) void dudc_final(
    const float* __restrict__ ws_multi, const float* __restrict__ ws_single,
    const float* __restrict__ para, float* __restrict__ out)
{
  const int lane = threadIdx.x;
  float a = 0.f, b = 0.f;
#pragma unroll
  for (int k = 0; k < 16; ++k) {
    float4 va = ((const float4*)ws_multi)[lane + (k << 6)];
    float4 vb = ((const float4*)ws_single)[lane + (k << 6)];
    a += (va.x + va.y) + (va.z + va.w);
    b += (vb.x + vb.y) + (vb.z + vb.w);
  }
#pragma unroll
  for (int o = 32; o > 0; o >>= 1) { a += __shfl_down(a, o); b += __shfl_down(b, o); }
  if (lane == 0) {
    float lmulti  = a * (1.f / B_);
    float lsingle = b * (1.f / (B_ * K_));
    float p = para[0];
    out[0] = p * lmulti + (1.f - p) * lsingle;
  }
}

extern "C" void kernel_launch(void* const* d_in, const int* in_sizes, int n_in,
                              void* d_out, int out_size, void* d_ws, size_t ws_size,
                              hipStream_t stream) {
  const float* out1    = (const float*)d_in[0];
  const float* out2    = (const float*)d_in[1];
  const float* para    = (const float*)d_in[2];
  // d_in[3] (target) intentionally unused: negativity derived from pos_idx
  const int*   pos_idx = (const int*)d_in[4];

  float* ws_multi  = (float*)d_ws;
  float* ws_single = ws_multi + B_;

  dudc_rows<<<B_ / 4, 256, 0, stream>>>(out1, out2, pos_idx, ws_multi, ws_single);
  dudc_final<<<1, 64, 0, stream>>>(ws_multi, ws_single, para, (float*)d_out);
}

// Round 7
// 97.197 us; speedup vs baseline: 1.0243x; 1.0243x over previous
//
#include <hip/hip_runtime.h>

// DUDCLoss: B=4096, C=1024, K=8, eps=1e-5
// loss = para*loss_multi + (1-para)*loss_single
//
// Exact identity: log(e_c/Z_j + eps) = log(e_c + eps*Z_j) - log(Z_j), Z_j = Sneg + pe_j.
// j-elimination (validated R3/R4/R6, absmax 0.0): a_c = e_c + eps*Sneg, d_j = eps*pe_j <= 1e-5,
//   log(a_c + d_j) ~= log(a_c) + d_j/a_c - 0.5 (d_j/a_c)^2
// => 6 j-independent reductions (L,R,Q each direction).
// target input never read: masked sums = unmasked sums - positive-column terms
// recomputed bitwise-identically from x[pos] (lanes 0..7).
// sigmoid reuses e = exp(x-m):  sigmoid(x) = e/(e + exp(-m))  (one exp per row).
//
// Structure: wave-per-row, shuffle-only reductions, no LDS/barriers/atomics.
// R3 lesson: per-block same-address atomics + threadfence serialized the grid.
// R4 lesson: harness overhead (256MB ws 0xAA poison at ~6.3TB/s = ~43us + input
//   restore + graph gaps) dominates total; kernels are ~10-13us of ~93us.
// R6 lesson: nt loads REGRESSED (+6us) — they evict the rows from L2 before the
//   lanes-0..7 positive-logit gather re-reads them. Keep loads cacheable.

constexpr int B_ = 4096;
constexpr int C_ = 1024;
constexpr int K_ = 8;
constexpr float EPSF = 1e-5f;
constexpr float L2E = 1.44269504088896340736f;  // log2(e)
constexpr float LN2 = 0.69314718055994530942f;  // ln(2)

// v_exp_f32: 2^x ; v_log_f32: log2(x) ; v_rcp_f32: 1/x
#if __has_builtin(__builtin_amdgcn_exp2f)
__device__ __forceinline__ float fexp2(float x) { return __builtin_amdgcn_exp2f(x); }
#else
__device__ __forceinline__ float fexp2(float x) { return exp2f(x); }
#endif
#if __has_builtin(__builtin_amdgcn_logf)
__device__ __forceinline__ float flog2(float x) { return __builtin_amdgcn_logf(x); }
#else
__device__ __forceinline__ float flog2(float x) { return log2f(x); }
#endif
#if __has_builtin(__builtin_amdgcn_rcpf)
__device__ __forceinline__ float frcp(float x) { return __builtin_amdgcn_rcpf(x); }
#else
__device__ __forceinline__ float frcp(float x) { return 1.0f / x; }
#endif

__global__ __launch_bounds__(256) void dudc_rows(
    const float* __restrict__ out1, const float* __restrict__ out2,
    const int* __restrict__ pos_idx,
    float* __restrict__ ws_multi, float* __restrict__ ws_single)
{
  const int t = threadIdx.x;
  const int wid = t >> 6, lane = t & 63;
  const int row = (blockIdx.x << 2) + wid;

  const float* x1p = out1 + (size_t)row * C_;
  const float* x2p = out2 + (size_t)row * C_;

  // lane owns columns 4*lane + 256*u, u=0..3 (each dwordx4 load is 1KB coalesced)
  float x1[16], x2[16];
#pragma unroll
  for (int u = 0; u < 4; ++u) {
    float4 a = ((const float4*)x1p)[lane + (u << 6)];
    float4 b = ((const float4*)x2p)[lane + (u << 6)];
    x1[4*u+0]=a.x; x1[4*u+1]=a.y; x1[4*u+2]=a.z; x1[4*u+3]=a.w;
    x2[4*u+0]=b.x; x2[4*u+1]=b.y; x2[4*u+2]=b.z; x2[4*u+3]=b.w;
  }

  // positive logits (lanes 0..7; rows are L1/L2-hot from the vector loads)
  float xp1 = 0.f, xp2 = 0.f;
  if (lane < K_) {
    int p = pos_idx[row * K_ + lane];
    xp1 = x1p[p];
    xp2 = x2p[p];
  }

  // ---- row max (butterfly -> all lanes) ----
  float m1 = x1[0], m2 = x2[0];
#pragma unroll
  for (int i = 1; i < 16; ++i) { m1 = fmaxf(m1, x1[i]); m2 = fmaxf(m2, x2[i]); }
#pragma unroll
  for (int o = 1; o < 64; o <<= 1) {
    m1 = fmaxf(m1, __shfl_xor(m1, o));
    m2 = fmaxf(m2, __shfl_xor(m2, o));
  }
  const float m1l = m1 * L2E, m2l = m2 * L2E;
  const float c1 = fexp2(-m1l);  // exp(-m1): sigmoid(x) = e/(e + c)
  const float c2 = fexp2(-m2l);

  float pe1 = 0.f, pe2 = 0.f;
  if (lane < K_) {
    pe1 = fexp2(__builtin_fmaf(xp1, L2E, -m1l));  // identical ops to e at pos
    pe2 = fexp2(__builtin_fmaf(xp2, L2E, -m2l));
  }

  // ---- exps (overwrite x), unmasked sums, sigmoid-CE ----
  float S1 = 0.f, S2 = 0.f, lm2 = 0.f;
#pragma unroll
  for (int i = 0; i < 16; ++i) {
    float e1 = fexp2(__builtin_fmaf(x1[i], L2E, -m1l));
    float e2 = fexp2(__builtin_fmaf(x2[i], L2E, -m2l));
    float s1 = e1 * frcp(e1 + c1);   // sigmoid(x1) exactly
    float s2 = e2 * frcp(e2 + c2);
    lm2 += s1 * flog2(s2 + EPSF) + s2 * flog2(s1 + EPSF);
    S1 += e1; S2 += e2;
    x1[i] = e1; x2[i] = e2;
  }
  // P1/P2 live only in lanes 0..7: 3 xor rounds + broadcast from lane 0
  float P1 = pe1, P2 = pe2;
#pragma unroll
  for (int o = 1; o < 8; o <<= 1) { P1 += __shfl_xor(P1, o); P2 += __shfl_xor(P2, o); }
  P1 = __shfl(P1, 0); P2 = __shfl(P2, 0);
#pragma unroll
  for (int o = 1; o < 64; o <<= 1) {
    S1 += __shfl_xor(S1, o);  S2 += __shfl_xor(S2, o);
    lm2 += __shfl_xor(lm2, o);
  }
  const float Sn1 = S1 - P1, Sn2 = S2 - P2;   // negative-set sums
  const float es1 = EPSF * Sn1, es2 = EPSF * Sn2;

  // ---- hot loop: 6 unmasked reductions ----
  float L12=0.f, R12=0.f, Q12=0.f, L21=0.f, R21=0.f, Q21=0.f;
#pragma unroll
  for (int i = 0; i < 16; ++i) {
    float a1 = x1[i] + es1, a2 = x2[i] + es2;
    float l1 = flog2(a1),  l2 = flog2(a2);
    float r1 = frcp(a1),   r2 = frcp(a2);
    L12 = __builtin_fmaf(x1[i], l2, L12);
    float t12 = x1[i] * r2;  R12 += t12;  Q12 = __builtin_fmaf(t12, r2, Q12);
    L21 = __builtin_fmaf(x2[i], l1, L21);
    float t21 = x2[i] * r1;  R21 += t21;  Q21 = __builtin_fmaf(t21, r1, Q21);
  }
#pragma unroll
  for (int o = 1; o < 64; o <<= 1) {
    L12 += __shfl_xor(L12,o); R12 += __shfl_xor(R12,o); Q12 += __shfl_xor(Q12,o);
    L21 += __shfl_xor(L21,o); R21 += __shfl_xor(R21,o); Q21 += __shfl_xor(Q21,o);
  }

  // ---- subtract the K positive columns' contributions (lanes 0..7) ----
  float cL12=0.f,cR12=0.f,cQ12=0.f,cL21=0.f,cR21=0.f,cQ21=0.f;
  if (lane < K_) {
    float a2p = pe2 + es2, a1p = pe1 + es1;
    float r2p = frcp(a2p), r1p = frcp(a1p);
    cL12 = pe1 * flog2(a2p);  cR12 = pe1 * r2p;  cQ12 = cR12 * r2p;
    cL21 = pe2 * flog2(a1p);  cR21 = pe2 * r1p;  cQ21 = cR21 * r1p;
  }
#pragma unroll
  for (int o = 1; o < 8; o <<= 1) {
    cL12 += __shfl_xor(cL12,o); cR12 += __shfl_xor(cR12,o); cQ12 += __shfl_xor(cQ12,o);
    cL21 += __shfl_xor(cL21,o); cR21 += __shfl_xor(cR21,o); cQ21 += __shfl_xor(cQ21,o);
  }

  // ---- per-j epilogue (lane = j) ----
  float contv = 0.f;
  if (lane < K_) {
    float sL12 = L12 - cL12, sR12 = R12 - cR12, sQ12 = Q12 - cQ12;
    float sL21 = L21 - cL21, sR21 = R21 - cR21, sQ21 = Q21 - cQ21;
    float Z1 = Sn1 + pe1, Z2 = Sn2 + pe2;
    float d1 = EPSF * pe1, d2 = EPSF * pe2;
    float T1 = LN2*sL12 + d2*sR12 - 0.5f*d2*d2*sQ12;
    float T2 = LN2*sL21 + d1*sR21 - 0.5f*d1*d1*sQ21;
    float pt1 = pe1 * (LN2 * flog2(pe2 + EPSF*Z2));
    float pt2 = pe2 * (LN2 * flog2(pe1 + EPSF*Z1));
    float x12 = -(T1 + pt1) * frcp(Z1) + LN2 * flog2(Z2);
    float x21 = -(T2 + pt2) * frcp(Z2) + LN2 * flog2(Z1);
    contv = x12 + x21;
  }
  contv += __shfl_down(contv, 4);
  contv += __shfl_down(contv, 2);
  contv += __shfl_down(contv, 1);
  if (lane == 0) {
    ws_multi[row]  = -LN2 * lm2;   // per-row sigmoid-CE sum (both directions)
    ws_single[row] = contv;        // per-row sum over K (scaled in final)
  }
}

// single-wave finalize: 8KB of partials, no LDS, no __syncthreads
__global__ __launch_bounds__(64) void dudc_final(
    const float* __restrict__ ws_multi, const float* __restrict__ ws_single,
    const float* __restrict__ para, float* __restrict__ out)
{
  const int lane = threadIdx.x;
  float a = 0.f, b = 0.f;
#pragma unroll
  for (int k = 0; k < 16; ++k) {
    float4 va = ((const float4*)ws_multi)[lane + (k << 6)];
    float4 vb = ((const float4*)ws_single)[lane + (k << 6)];
    a += (va.x + va.y) + (va.z + va.w);
    b += (vb.x + vb.y) + (vb.z + vb.w);
  }
#pragma unroll
  for (int o = 32; o > 0; o >>= 1) { a += __shfl_down(a, o); b += __shfl_down(b, o); }
  if (lane == 0) {
    float lmulti  = a * (1.f / B_);
    float lsingle = b * (1.f / (B_ * K_));
    float p = para[0];
    out[0] = p * lmulti + (1.f - p) * lsingle;
  }
}

extern "C" void kernel_launch(void* const* d_in, const int* in_sizes, int n_in,
                              void* d_out, int out_size, void* d_ws, size_t ws_size,
                              hipStream_t stream) {
  const float* out1    = (const float*)d_in[0];
  const float* out2    = (const float*)d_in[1];
  const float* para    = (const float*)d_in[2];
  // d_in[3] (target) intentionally unused: negativity derived from pos_idx
  const int*   pos_idx = (const int*)d_in[4];

  float* ws_multi  = (float*)d_ws;
  float* ws_single = ws_multi + B_;

  dudc_rows<<<B_ / 4, 256, 0, stream>>>(out1, out2, pos_idx, ws_multi, ws_single);
  dudc_final<<<1, 64, 0, stream>>>(ws_multi, ws_single, para, (float*)d_out);
}